// Round 3
// baseline (410.032 us; speedup 1.0000x reference)
//
#include <hip/hip_runtime.h>
#include <hip/hip_bf16.h>
#include <math.h>

#define NN    65536
#define EE    524288
#define BBG   64
#define PERG  1024
#define KKEEP 820
#define FF    128

// ---------------- degree histogram ----------------
__global__ __launch_bounds__(256) void k_deg(const int* __restrict__ ei,
                                             int* __restrict__ deg) {
    int e = blockIdx.x * 256 + threadIdx.x;
    if (e < EE) atomicAdd(&deg[ei[EE + e]], 1);
}

// ---------------- 3-stage exclusive scan of deg -> starts ----------------
__global__ __launch_bounds__(256) void k_scan1(const int* __restrict__ deg,
                                               int* __restrict__ spart,
                                               int* __restrict__ bsum) {
    int t = threadIdx.x;
    int i = blockIdx.x * 256 + t;
    __shared__ int sh[256];
    int v = deg[i];
    sh[t] = v;
    __syncthreads();
    for (int o = 1; o < 256; o <<= 1) {
        int u = (t >= o) ? sh[t - o] : 0;
        __syncthreads();
        sh[t] += u;
        __syncthreads();
    }
    spart[i] = sh[t];
    if (t == 255) bsum[blockIdx.x] = sh[255];
}

__global__ __launch_bounds__(256) void k_scan2(const int* __restrict__ bsum,
                                               int* __restrict__ boff) {
    int t = threadIdx.x;
    __shared__ int sh[256];
    int v = bsum[t];
    sh[t] = v;
    __syncthreads();
    for (int o = 1; o < 256; o <<= 1) {
        int u = (t >= o) ? sh[t - o] : 0;
        __syncthreads();
        sh[t] += u;
        __syncthreads();
    }
    boff[t] = sh[t] - v;
}

__global__ __launch_bounds__(256) void k_scan3(const int* __restrict__ deg,
                                               const int* __restrict__ spart,
                                               const int* __restrict__ boff,
                                               int* __restrict__ starts,
                                               int* __restrict__ cursor) {
    int i = blockIdx.x * 256 + threadIdx.x;
    int st = spart[i] - deg[i] + boff[i >> 8];
    starts[i] = st;
    cursor[i] = st;
    if (i == 0) starts[NN] = EE;
}

// ---------------- scatter edges into CSR ----------------
__global__ __launch_bounds__(256) void k_scatter(const int* __restrict__ ei,
                                                 int* __restrict__ cursor,
                                                 int* __restrict__ ssrc) {
    int e = blockIdx.x * 256 + threadIdx.x;
    if (e >= EE) return;
    int s = ei[e];
    int d = ei[EE + e];
    int pos = atomicAdd(&cursor[d], 1);
    ssrc[pos] = s;
}

// ---------------- y = x@Wl^T ; z = x@Wr^T + bl (one pass over x) ----------------
// 64-node tile, 256 threads; o = tx + 16*j strided outputs; Wt transposed in LDS
__global__ __launch_bounds__(256) void k_gemm2(const float* __restrict__ x,
                                               const float* __restrict__ Wl,
                                               const float* __restrict__ Wr,
                                               const float* __restrict__ bl,
                                               float* __restrict__ y,
                                               float* __restrict__ hz) {
    __shared__ float As[64][36];
    __shared__ float Wt[2][128][36];
    const int tid = threadIdx.x;
    const int n0  = blockIdx.x * 64;
    const int tx  = tid & 15;
    const int ty  = tid >> 4;     // 0..15, nodes ty*4..ty*4+3

    float acc0[4][8], acc1[4][8];
#pragma unroll
    for (int i = 0; i < 4; ++i)
#pragma unroll
        for (int j = 0; j < 8; ++j) { acc0[i][j] = 0.f; acc1[i][j] = 0.f; }

    const int kk_s = tid & 31;
    const int rb   = tid >> 5;    // 0..7

    for (int c = 0; c < 4; ++c) {
        const int k0 = c * 32;
        __syncthreads();
#pragma unroll
        for (int i = 0; i < 8; ++i) {
            int r = rb + i * 8;
            As[r][kk_s] = x[(size_t)(n0 + r) * FF + k0 + kk_s];
        }
#pragma unroll
        for (int i = 0; i < 16; ++i) {
            int o = rb + i * 8;
            Wt[0][o][kk_s] = Wl[o * FF + k0 + kk_s];
            Wt[1][o][kk_s] = Wr[o * FF + k0 + kk_s];
        }
        __syncthreads();
#pragma unroll
        for (int kk = 0; kk < 32; ++kk) {
            float a[4];
#pragma unroll
            for (int i = 0; i < 4; ++i) a[i] = As[ty * 4 + i][kk];
#pragma unroll
            for (int j = 0; j < 8; ++j) {
                float wl = Wt[0][tx + 16 * j][kk];
                float wr = Wt[1][tx + 16 * j][kk];
#pragma unroll
                for (int i = 0; i < 4; ++i) {
                    acc0[i][j] = fmaf(a[i], wl, acc0[i][j]);
                    acc1[i][j] = fmaf(a[i], wr, acc1[i][j]);
                }
            }
        }
    }

#pragma unroll
    for (int j = 0; j < 8; ++j) {
        int o = tx + 16 * j;
        float b = bl[o];
#pragma unroll
        for (int i = 0; i < 4; ++i) {
            size_t n = (size_t)(n0 + ty * 4 + i);
            y[n * FF + o]  = acc0[i][j];
            hz[n * FF + o] = acc1[i][j] + b;
        }
    }
}

// ---------------- h = (sum y[src])/deg + z  (in place over hz) + BN stats ----------------
__global__ __launch_bounds__(256) void k_hgather(const float* __restrict__ y,
                                                 const int* __restrict__ ssrc,
                                                 const int* __restrict__ starts,
                                                 float* __restrict__ hz,
                                                 float* __restrict__ stats) {
    int w    = threadIdx.x >> 6;
    int lane = threadIdx.x & 63;
    int nbase = blockIdx.x * 32 + w * 8;
    float s1a = 0.f, s1b = 0.f, s2a = 0.f, s2b = 0.f;
    for (int q = 0; q < 8; ++q) {
        int n  = nbase + q;
        int d0 = starts[n], d1 = starts[n + 1];
        float2 acc = make_float2(0.f, 0.f);
        int e = d0;
        for (; e + 1 < d1; e += 2) {
            int sA = ssrc[e], sB = ssrc[e + 1];
            float2 vA = *(const float2*)(y + (size_t)sA * FF + lane * 2);
            float2 vB = *(const float2*)(y + (size_t)sB * FF + lane * 2);
            acc.x += vA.x + vB.x;
            acc.y += vA.y + vB.y;
        }
        if (e < d1) {
            int sA = ssrc[e];
            float2 vA = *(const float2*)(y + (size_t)sA * FF + lane * 2);
            acc.x += vA.x;
            acc.y += vA.y;
        }
        float inv = 1.0f / fmaxf((float)(d1 - d0), 1.0f);
        float2 z = *(const float2*)(hz + (size_t)n * FF + lane * 2);
        float h0 = acc.x * inv + z.x;
        float h1 = acc.y * inv + z.y;
        *(float2*)(hz + (size_t)n * FF + lane * 2) = make_float2(h0, h1);
        s1a += h0; s1b += h1;
        s2a += h0 * h0; s2b += h1 * h1;
    }
    __shared__ float sh1[4][128], sh2[4][128];
    sh1[w][lane * 2]     = s1a;
    sh1[w][lane * 2 + 1] = s1b;
    sh2[w][lane * 2]     = s2a;
    sh2[w][lane * 2 + 1] = s2b;
    __syncthreads();
    int tid = threadIdx.x;
    if (tid < 128) {
        float a = sh1[0][tid] + sh1[1][tid] + sh1[2][tid] + sh1[3][tid];
        float b = sh2[0][tid] + sh2[1][tid] + sh2[2][tid] + sh2[3][tid];
        atomicAdd(&stats[tid], a);
        atomicAdd(&stats[128 + tid], b);
    }
}

// stats: [0:128) sum, [128:256) sumsq, [256:384) scale, [384:512) shift, [512:640) attn/||attn||
__global__ __launch_bounds__(128) void k_bnparam(const float* __restrict__ gamma,
                                                 const float* __restrict__ beta,
                                                 const float* __restrict__ attn,
                                                 float* __restrict__ stats) {
    int f = threadIdx.x;
    float mean = stats[f] / (float)NN;
    float var  = stats[128 + f] / (float)NN - mean * mean;
    float inv  = 1.0f / sqrtf(var + 1e-5f);
    float sc   = gamma[f] * inv;
    stats[256 + f] = sc;
    stats[384 + f] = beta[f] - mean * sc;
    __shared__ float sa[128];
    float a = attn[f];
    sa[f] = a * a;
    __syncthreads();
    for (int s = 64; s > 0; s >>= 1) {
        if (f < s) sa[f] += sa[f + s];
        __syncthreads();
    }
    stats[512 + f] = a / sqrtf(sa[0]);
}

// ---------------- normalize + relu (in place) + score ----------------
__global__ __launch_bounds__(256) void k_norm(float* __restrict__ h,
                                              const float* __restrict__ stats,
                                              float* __restrict__ score) {
    int node = (blockIdx.x * 256 + threadIdx.x) >> 6;
    int lane = threadIdx.x & 63;
    float sc0 = stats[256 + lane],      sh0 = stats[384 + lane];
    float sc1 = stats[256 + 64 + lane], sh1 = stats[384 + 64 + lane];
    float a0  = stats[512 + lane],      a1  = stats[512 + 64 + lane];
    size_t base = (size_t)node * FF;
    float v0 = fmaxf(h[base + lane] * sc0 + sh0, 0.f);
    float v1 = fmaxf(h[base + 64 + lane] * sc1 + sh1, 0.f);
    h[base + lane]      = v0;
    h[base + 64 + lane] = v1;
    float s = v0 * a0 + v1 * a1;
#pragma unroll
    for (int off = 32; off > 0; off >>= 1) s += __shfl_down(s, off);
    if (lane == 0) score[node] = s;
}

// ---------------- per-graph bitonic sort (desc, stable) + perm/node_map ----------------
__global__ __launch_bounds__(1024) void k_topk(const float* __restrict__ score,
                                               int* __restrict__ nmap,
                                               int* __restrict__ plist,
                                               float* __restrict__ out_batch) {
    __shared__ unsigned long long keys[PERG];
    int b = blockIdx.x;
    int t = threadIdx.x;
    float s = score[b * PERG + t];
    unsigned u = __float_as_uint(s);
    u = (u & 0x80000000u) ? ~u : (u | 0x80000000u);
    keys[t] = ((unsigned long long)u << 10) | (unsigned long long)(1023 - t);
    __syncthreads();
    for (int k = 2; k <= PERG; k <<= 1) {
        for (int j = k >> 1; j > 0; j >>= 1) {
            int l = t ^ j;
            if (l > t) {
                bool asc = ((t & k) != 0);
                unsigned long long a = keys[t], c = keys[l];
                if ((a > c) == asc) { keys[t] = c; keys[l] = a; }
            }
            __syncthreads();
        }
    }
    if (t < KKEEP) {
        int idx = 1023 - (int)(keys[t] & 1023ull);
        int g   = b * PERG + idx;
        int nid = b * KKEEP + t;
        plist[nid]     = g;
        nmap[g]        = nid;
        out_batch[nid] = (float)b;
    }
}

// ---------------- hp = h[perm] * tanh(score[perm]) ----------------
__global__ __launch_bounds__(256) void k_hp(const float* __restrict__ h,
                                            const float* __restrict__ score,
                                            const int* __restrict__ plist,
                                            float* __restrict__ out_hp) {
    int row  = blockIdx.x * 4 + (threadIdx.x >> 6);
    int lane = threadIdx.x & 63;
    int g    = plist[row];
    float tt = tanhf(score[g]);
    float2 v = *(const float2*)(h + (size_t)g * FF + lane * 2);
    v.x *= tt;
    v.y *= tt;
    *(float2*)(out_hp + (size_t)row * FF + lane * 2) = v;
}

// ---------------- per-graph sum & max pooling ----------------
__global__ __launch_bounds__(256) void k_flat(const float* __restrict__ hp,
                                              float* __restrict__ out_flat) {
    int b   = blockIdx.x;
    int tid = threadIdx.x;
    int f   = tid & 127;
    int p   = tid >> 7;
    float s = 0.f, m = -INFINITY;
    const float* base = hp + (size_t)b * KKEEP * FF;
    for (int r = p; r < KKEEP; r += 2) {
        float v = base[r * FF + f];
        s += v;
        m = fmaxf(m, v);
    }
    __shared__ float ss[256], mm[256];
    ss[tid] = s;
    mm[tid] = m;
    __syncthreads();
    if (p == 0) {
        out_flat[b * 256 + f]       = ss[tid] + ss[tid + 128];
        out_flat[b * 256 + 128 + f] = fmaxf(mm[tid], mm[tid + 128]);
    }
}

// ---------------- edge reindex ----------------
__global__ __launch_bounds__(256) void k_edge(const int* __restrict__ ei,
                                              const int* __restrict__ nmap,
                                              float* __restrict__ out_edge) {
    int e = blockIdx.x * 256 + threadIdx.x;
    if (e >= EE) return;
    int s  = ei[e];
    int d  = ei[EE + e];
    int ns = nmap[s];
    int nd = nmap[d];
    bool keep = (ns >= 0) && (nd >= 0);
    out_edge[e]      = keep ? (float)ns : -1.0f;
    out_edge[EE + e] = keep ? (float)nd : -1.0f;
}

extern "C" void kernel_launch(void* const* d_in, const int* in_sizes, int n_in,
                              void* d_out, int out_size, void* d_ws, size_t ws_size,
                              hipStream_t stream) {
    const float* x    = (const float*)d_in[0];
    const int*   ei   = (const int*)d_in[1];
    const float* Wl   = (const float*)d_in[3];
    const float* bl   = (const float*)d_in[4];
    const float* Wr   = (const float*)d_in[5];
    const float* gam  = (const float*)d_in[6];
    const float* bet  = (const float*)d_in[7];
    const float* attn = (const float*)d_in[8];

    // workspace layout
    float* y      = (float*)d_ws;                  // NN*FF
    float* hz     = y + (size_t)NN * FF;           // NN*FF (z, then h in-place)
    float* score  = hz + (size_t)NN * FF;          // NN     (aliased: deg)
    int*   nmap   = (int*)(score + NN);            // NN     (aliased: spart)
    int*   plist  = nmap + NN;                     // BBG*KKEEP
    float* stats  = (float*)(plist + BBG * KKEEP); // 640
    int*   starts = (int*)(stats + 640);           // NN+1
    int*   cursor = starts + NN + 1;               // NN
    int*   ssrc   = cursor + NN;                   // EE
    int*   bsum   = ssrc + EE;                     // 256
    int*   boff   = bsum + 256;                    // 256

    int* deg   = (int*)score;   // dead before k_norm writes score
    int* spart = (int*)nmap;    // dead before nmap memset

    // output layout (all float32)
    float* out       = (float*)d_out;
    float* out_hp    = out;                                // 52480*128
    float* out_flat  = out_hp + (size_t)BBG * KKEEP * FF;  // 64*256
    float* out_edge  = out_flat + BBG * 256;               // 2*EE
    float* out_batch = out_edge + 2 * EE;                  // 52480

    hipMemsetAsync(deg, 0, (size_t)NN * sizeof(int), stream);
    hipMemsetAsync(stats, 0, 640 * sizeof(float), stream);

    k_deg<<<EE / 256, 256, 0, stream>>>(ei, deg);
    k_scan1<<<256, 256, 0, stream>>>(deg, spart, bsum);
    k_scan2<<<1, 256, 0, stream>>>(bsum, boff);
    k_scan3<<<256, 256, 0, stream>>>(deg, spart, boff, starts, cursor);
    k_scatter<<<EE / 256, 256, 0, stream>>>(ei, cursor, ssrc);

    hipMemsetAsync(nmap, 0xFF, (size_t)NN * sizeof(int), stream);  // spart dead now

    k_gemm2<<<NN / 64, 256, 0, stream>>>(x, Wl, Wr, bl, y, hz);
    k_hgather<<<NN / 32, 256, 0, stream>>>(y, ssrc, starts, hz, stats);
    k_bnparam<<<1, 128, 0, stream>>>(gam, bet, attn, stats);
    k_norm<<<NN / 4, 256, 0, stream>>>(hz, stats, score);
    k_topk<<<BBG, 1024, 0, stream>>>(score, nmap, plist, out_batch);
    k_hp<<<(BBG * KKEEP) / 4, 256, 0, stream>>>(hz, score, plist, out_hp);
    k_flat<<<BBG, 256, 0, stream>>>(out_hp, out_flat);
    k_edge<<<EE / 256, 256, 0, stream>>>(ei, nmap, out_edge);
}

// Round 4
// 376.887 us; speedup vs baseline: 1.0879x; 1.0879x over previous
//
#include <hip/hip_runtime.h>
#include <hip/hip_bf16.h>
#include <math.h>

#define NN    65536
#define EE    524288
#define BBG   64
#define PERG  1024
#define KKEEP 820
#define FF    128
#define EPSBN 1e-5f

// ---------------- degree histogram ----------------
__global__ __launch_bounds__(256) void k_deg(const int* __restrict__ ei,
                                             int* __restrict__ deg) {
    int e = blockIdx.x * 256 + threadIdx.x;
    if (e < EE) atomicAdd(&deg[ei[EE + e]], 1);
}

// ---------------- 3-stage exclusive scan of deg -> starts ----------------
__global__ __launch_bounds__(256) void k_scan1(const int* __restrict__ deg,
                                               int* __restrict__ spart,
                                               int* __restrict__ bsum) {
    int t = threadIdx.x;
    int i = blockIdx.x * 256 + t;
    __shared__ int sh[256];
    int v = deg[i];
    sh[t] = v;
    __syncthreads();
    for (int o = 1; o < 256; o <<= 1) {
        int u = (t >= o) ? sh[t - o] : 0;
        __syncthreads();
        sh[t] += u;
        __syncthreads();
    }
    spart[i] = sh[t];
    if (t == 255) bsum[blockIdx.x] = sh[255];
}

__global__ __launch_bounds__(256) void k_scan2(const int* __restrict__ bsum,
                                               int* __restrict__ boff) {
    int t = threadIdx.x;
    __shared__ int sh[256];
    int v = bsum[t];
    sh[t] = v;
    __syncthreads();
    for (int o = 1; o < 256; o <<= 1) {
        int u = (t >= o) ? sh[t - o] : 0;
        __syncthreads();
        sh[t] += u;
        __syncthreads();
    }
    boff[t] = sh[t] - v;
}

__global__ __launch_bounds__(256) void k_scan3(const int* __restrict__ deg,
                                               const int* __restrict__ spart,
                                               const int* __restrict__ boff,
                                               int* __restrict__ starts,
                                               int* __restrict__ cursor) {
    int i = blockIdx.x * 256 + threadIdx.x;
    int st = spart[i] - deg[i] + boff[i >> 8];
    starts[i] = st;
    cursor[i] = st;
    if (i == 0) starts[NN] = EE;
}

// ---------------- scatter edges into CSR ----------------
__global__ __launch_bounds__(256) void k_scatter(const int* __restrict__ ei,
                                                 int* __restrict__ cursor,
                                                 int* __restrict__ ssrc) {
    int e = blockIdx.x * 256 + threadIdx.x;
    if (e >= EE) return;
    int s = ei[e];
    int d = ei[EE + e];
    int pos = atomicAdd(&cursor[d], 1);
    ssrc[pos] = s;
}

// ---------------- y = x@Wl^T ; hz = x@Wr^T + bl ----------------
// 128-node tile, 256 threads. k-major LDS, b128 reads only in inner loop.
// thread: tx=tid&15 -> node quads {tx*4, 64+tx*4}; ty=tid>>4 -> output octet ty*8
__global__ __launch_bounds__(256) void k_gemm3(const float* __restrict__ x,
                                               const float* __restrict__ Wl,
                                               const float* __restrict__ Wr,
                                               const float* __restrict__ bl,
                                               float* __restrict__ y,
                                               float* __restrict__ hz) {
    __shared__ float As[32][132];   // [k][node 0..127]
    __shared__ float Ws[32][260];   // [k][o]; o<128: Wl, o>=128: Wr
    const int tid = threadIdx.x;
    const int n0  = blockIdx.x * 128;
    const int tx  = tid & 15;
    const int ty  = tid >> 4;       // 0..15
    const int t8  = tid & 7;
    const int r32 = tid >> 3;       // 0..31
    const int st  = tid & 3;        // write-stagger

    float accl[8][8], accr[8][8];
#pragma unroll
    for (int i = 0; i < 8; ++i)
#pragma unroll
        for (int j = 0; j < 8; ++j) { accl[i][j] = 0.f; accr[i][j] = 0.f; }

    for (int c = 0; c < 4; ++c) {
        const int k0 = c * 32;
        __syncthreads();
        // stage x tile: 128 rows x 32 k, transpose to k-major
#pragma unroll
        for (int p = 0; p < 4; ++p) {
            int row = r32 + p * 32;
            float4 v = *(const float4*)&x[(size_t)(n0 + row) * FF + k0 + t8 * 4];
            float vv[4] = {v.x, v.y, v.z, v.w};
#pragma unroll
            for (int c0 = 0; c0 < 4; ++c0) {
                int cc = (c0 + st) & 3;
                As[t8 * 4 + cc][row] = vv[cc];
            }
        }
        // stage W tile: 256 rows x 32 k (Wl rows 0..127, Wr rows 128..255)
#pragma unroll
        for (int p = 0; p < 8; ++p) {
            int o = r32 + p * 32;
            const float* Wsrc = (o < 128) ? (Wl + (size_t)o * FF)
                                          : (Wr + (size_t)(o - 128) * FF);
            float4 v = *(const float4*)&Wsrc[k0 + t8 * 4];
            float vv[4] = {v.x, v.y, v.z, v.w};
#pragma unroll
            for (int c0 = 0; c0 < 4; ++c0) {
                int cc = (c0 + st) & 3;
                Ws[t8 * 4 + cc][o] = vv[cc];
            }
        }
        __syncthreads();
#pragma unroll
        for (int kk = 0; kk < 32; ++kk) {
            float4 a0 = *(const float4*)&As[kk][tx * 4];
            float4 a1 = *(const float4*)&As[kk][64 + tx * 4];
            float4 w0 = *(const float4*)&Ws[kk][ty * 8];
            float4 w1 = *(const float4*)&Ws[kk][ty * 8 + 4];
            float4 u0 = *(const float4*)&Ws[kk][128 + ty * 8];
            float4 u1 = *(const float4*)&Ws[kk][128 + ty * 8 + 4];
            float av[8] = {a0.x, a0.y, a0.z, a0.w, a1.x, a1.y, a1.z, a1.w};
            float wl8[8] = {w0.x, w0.y, w0.z, w0.w, w1.x, w1.y, w1.z, w1.w};
            float wr8[8] = {u0.x, u0.y, u0.z, u0.w, u1.x, u1.y, u1.z, u1.w};
#pragma unroll
            for (int i = 0; i < 8; ++i)
#pragma unroll
                for (int j = 0; j < 8; ++j) {
                    accl[i][j] = fmaf(av[i], wl8[j], accl[i][j]);
                    accr[i][j] = fmaf(av[i], wr8[j], accr[i][j]);
                }
        }
    }

    float bj[8];
#pragma unroll
    for (int j = 0; j < 8; ++j) bj[j] = bl[ty * 8 + j];

#pragma unroll
    for (int i = 0; i < 8; ++i) {
        int n = n0 + ((i < 4) ? (tx * 4 + i) : (64 + tx * 4 + i - 4));
        size_t base = (size_t)n * FF + ty * 8;
        *(float4*)&y[base]     = make_float4(accl[i][0], accl[i][1], accl[i][2], accl[i][3]);
        *(float4*)&y[base + 4] = make_float4(accl[i][4], accl[i][5], accl[i][6], accl[i][7]);
        *(float4*)&hz[base]     = make_float4(accr[i][0] + bj[0], accr[i][1] + bj[1],
                                              accr[i][2] + bj[2], accr[i][3] + bj[3]);
        *(float4*)&hz[base + 4] = make_float4(accr[i][4] + bj[4], accr[i][5] + bj[5],
                                              accr[i][6] + bj[6], accr[i][7] + bj[7]);
    }
}

// ---------------- h = (sum y[src])/deg + z  (in place over hz) + BN stats ----------------
__global__ __launch_bounds__(256) void k_hgather(const float* __restrict__ y,
                                                 const int* __restrict__ ssrc,
                                                 const int* __restrict__ starts,
                                                 float* __restrict__ hz,
                                                 float* __restrict__ stats) {
    int w    = threadIdx.x >> 6;
    int lane = threadIdx.x & 63;
    int nbase = blockIdx.x * 32 + w * 8;
    float s1a = 0.f, s1b = 0.f, s2a = 0.f, s2b = 0.f;
    for (int q = 0; q < 8; ++q) {
        int n  = nbase + q;
        int d0 = starts[n], d1 = starts[n + 1];
        float2 acc = make_float2(0.f, 0.f);
        int e = d0;
        for (; e + 1 < d1; e += 2) {
            int sA = ssrc[e], sB = ssrc[e + 1];
            float2 vA = *(const float2*)(y + (size_t)sA * FF + lane * 2);
            float2 vB = *(const float2*)(y + (size_t)sB * FF + lane * 2);
            acc.x += vA.x + vB.x;
            acc.y += vA.y + vB.y;
        }
        if (e < d1) {
            int sA = ssrc[e];
            float2 vA = *(const float2*)(y + (size_t)sA * FF + lane * 2);
            acc.x += vA.x;
            acc.y += vA.y;
        }
        float inv = 1.0f / fmaxf((float)(d1 - d0), 1.0f);
        float2 z = *(const float2*)(hz + (size_t)n * FF + lane * 2);
        float h0 = acc.x * inv + z.x;
        float h1 = acc.y * inv + z.y;
        *(float2*)(hz + (size_t)n * FF + lane * 2) = make_float2(h0, h1);
        s1a += h0; s1b += h1;
        s2a += h0 * h0; s2b += h1 * h1;
    }
    __shared__ float sh1[4][128], sh2[4][128];
    sh1[w][lane * 2]     = s1a;
    sh1[w][lane * 2 + 1] = s1b;
    sh2[w][lane * 2]     = s2a;
    sh2[w][lane * 2 + 1] = s2b;
    __syncthreads();
    int tid = threadIdx.x;
    if (tid < 128) {
        float a = sh1[0][tid] + sh1[1][tid] + sh1[2][tid] + sh1[3][tid];
        float b = sh2[0][tid] + sh2[1][tid] + sh2[2][tid] + sh2[3][tid];
        atomicAdd(&stats[tid], a);
        atomicAdd(&stats[128 + tid], b);
    }
}

// ---------------- score only (BN params computed inline, no h writeback) ----------------
// 256 threads = 8 rows/block; 32 lanes per row, float4 per lane
__global__ __launch_bounds__(256) void k_score(const float* __restrict__ h,
                                               const float* __restrict__ stats,
                                               const float* __restrict__ gamma,
                                               const float* __restrict__ beta,
                                               const float* __restrict__ attn,
                                               float* __restrict__ score) {
    int tid = threadIdx.x;
    int l32 = tid & 31;
    int n   = blockIdx.x * 8 + (tid >> 5);
    int f0  = l32 * 4;
    float4 su = *(const float4*)&stats[f0];
    float4 sq = *(const float4*)&stats[128 + f0];
    float4 g4 = *(const float4*)&gamma[f0];
    float4 b4 = *(const float4*)&beta[f0];
    float4 a4 = *(const float4*)&attn[f0];
    float an = a4.x * a4.x + a4.y * a4.y + a4.z * a4.z + a4.w * a4.w;
#pragma unroll
    for (int off = 16; off > 0; off >>= 1) an += __shfl_xor(an, off);
    float inva = 1.0f / sqrtf(an);
    float invN = 1.0f / (float)NN;
    float m0 = su.x * invN, m1 = su.y * invN, m2 = su.z * invN, m3 = su.w * invN;
    float sc0 = g4.x / sqrtf(sq.x * invN - m0 * m0 + EPSBN);
    float sc1 = g4.y / sqrtf(sq.y * invN - m1 * m1 + EPSBN);
    float sc2 = g4.z / sqrtf(sq.z * invN - m2 * m2 + EPSBN);
    float sc3 = g4.w / sqrtf(sq.w * invN - m3 * m3 + EPSBN);
    float4 hv = *(const float4*)&h[(size_t)n * FF + f0];
    float v0 = fmaxf((hv.x - m0) * sc0 + b4.x, 0.f);
    float v1 = fmaxf((hv.y - m1) * sc1 + b4.y, 0.f);
    float v2 = fmaxf((hv.z - m2) * sc2 + b4.z, 0.f);
    float v3 = fmaxf((hv.w - m3) * sc3 + b4.w, 0.f);
    float s = (v0 * a4.x + v1 * a4.y + v2 * a4.z + v3 * a4.w) * inva;
#pragma unroll
    for (int off = 16; off > 0; off >>= 1) s += __shfl_xor(s, off);
    if (l32 == 0) score[n] = s;
}

// ---------------- per-graph bitonic sort (desc, stable) + perm/node_map ----------------
__global__ __launch_bounds__(1024) void k_topk(const float* __restrict__ score,
                                               int* __restrict__ nmap,
                                               int* __restrict__ plist,
                                               float* __restrict__ out_batch) {
    __shared__ unsigned long long keys[PERG];
    int b = blockIdx.x;
    int t = threadIdx.x;
    float s = score[b * PERG + t];
    unsigned u = __float_as_uint(s);
    u = (u & 0x80000000u) ? ~u : (u | 0x80000000u);
    keys[t] = ((unsigned long long)u << 10) | (unsigned long long)(1023 - t);
    __syncthreads();
    for (int k = 2; k <= PERG; k <<= 1) {
        for (int j = k >> 1; j > 0; j >>= 1) {
            int l = t ^ j;
            if (l > t) {
                bool asc = ((t & k) != 0);
                unsigned long long a = keys[t], c = keys[l];
                if ((a > c) == asc) { keys[t] = c; keys[l] = a; }
            }
            __syncthreads();
        }
    }
    if (t < KKEEP) {
        int idx = 1023 - (int)(keys[t] & 1023ull);
        int g   = b * PERG + idx;
        int nid = b * KKEEP + t;
        plist[nid]     = g;
        nmap[g]        = nid;
        out_batch[nid] = (float)b;
    }
}

// ---------------- hp = BNrelu(h[perm]) * tanh(score[perm]) ----------------
__global__ __launch_bounds__(256) void k_hp(const float* __restrict__ h,
                                            const float* __restrict__ score,
                                            const int* __restrict__ plist,
                                            const float* __restrict__ stats,
                                            const float* __restrict__ gamma,
                                            const float* __restrict__ beta,
                                            float* __restrict__ out_hp) {
    int tid = threadIdx.x;
    int l32 = tid & 31;
    int row = blockIdx.x * 8 + (tid >> 5);
    int f0  = l32 * 4;
    float4 su = *(const float4*)&stats[f0];
    float4 sq = *(const float4*)&stats[128 + f0];
    float4 g4 = *(const float4*)&gamma[f0];
    float4 b4 = *(const float4*)&beta[f0];
    float invN = 1.0f / (float)NN;
    float m0 = su.x * invN, m1 = su.y * invN, m2 = su.z * invN, m3 = su.w * invN;
    float sc0 = g4.x / sqrtf(sq.x * invN - m0 * m0 + EPSBN);
    float sc1 = g4.y / sqrtf(sq.y * invN - m1 * m1 + EPSBN);
    float sc2 = g4.z / sqrtf(sq.z * invN - m2 * m2 + EPSBN);
    float sc3 = g4.w / sqrtf(sq.w * invN - m3 * m3 + EPSBN);
    int g  = plist[row];
    float tt = tanhf(score[g]);
    float4 hv = *(const float4*)&h[(size_t)g * FF + f0];
    float4 o;
    o.x = fmaxf((hv.x - m0) * sc0 + b4.x, 0.f) * tt;
    o.y = fmaxf((hv.y - m1) * sc1 + b4.y, 0.f) * tt;
    o.z = fmaxf((hv.z - m2) * sc2 + b4.z, 0.f) * tt;
    o.w = fmaxf((hv.w - m3) * sc3 + b4.w, 0.f) * tt;
    *(float4*)&out_hp[(size_t)row * FF + f0] = o;
}

// ---------------- per-graph sum & max pooling ----------------
__global__ __launch_bounds__(256) void k_flat(const float* __restrict__ hp,
                                              float* __restrict__ out_flat) {
    int b   = blockIdx.x;
    int tid = threadIdx.x;
    int f   = tid & 127;
    int p   = tid >> 7;
    float s = 0.f, m = -INFINITY;
    const float* base = hp + (size_t)b * KKEEP * FF;
    for (int r = p; r < KKEEP; r += 2) {
        float v = base[r * FF + f];
        s += v;
        m = fmaxf(m, v);
    }
    __shared__ float ss[256], mm[256];
    ss[tid] = s;
    mm[tid] = m;
    __syncthreads();
    if (p == 0) {
        out_flat[b * 256 + f]       = ss[tid] + ss[tid + 128];
        out_flat[b * 256 + 128 + f] = fmaxf(mm[tid], mm[tid + 128]);
    }
}

// ---------------- edge reindex ----------------
__global__ __launch_bounds__(256) void k_edge(const int* __restrict__ ei,
                                              const int* __restrict__ nmap,
                                              float* __restrict__ out_edge) {
    int e = blockIdx.x * 256 + threadIdx.x;
    if (e >= EE) return;
    int s  = ei[e];
    int d  = ei[EE + e];
    int ns = nmap[s];
    int nd = nmap[d];
    bool keep = (ns >= 0) && (nd >= 0);
    out_edge[e]      = keep ? (float)ns : -1.0f;
    out_edge[EE + e] = keep ? (float)nd : -1.0f;
}

extern "C" void kernel_launch(void* const* d_in, const int* in_sizes, int n_in,
                              void* d_out, int out_size, void* d_ws, size_t ws_size,
                              hipStream_t stream) {
    const float* x    = (const float*)d_in[0];
    const int*   ei   = (const int*)d_in[1];
    const float* Wl   = (const float*)d_in[3];
    const float* bl   = (const float*)d_in[4];
    const float* Wr   = (const float*)d_in[5];
    const float* gam  = (const float*)d_in[6];
    const float* bet  = (const float*)d_in[7];
    const float* attn = (const float*)d_in[8];

    // workspace layout
    float* y      = (float*)d_ws;                  // NN*FF
    float* hz     = y + (size_t)NN * FF;           // NN*FF (z, then h in-place)
    float* score  = hz + (size_t)NN * FF;          // NN     (aliased: deg)
    int*   nmap   = (int*)(score + NN);            // NN     (aliased: spart)
    int*   plist  = nmap + NN;                     // BBG*KKEEP
    float* stats  = (float*)(plist + BBG * KKEEP); // 256
    int*   starts = (int*)(stats + 640);           // NN+1
    int*   cursor = starts + NN + 1;               // NN
    int*   ssrc   = cursor + NN;                   // EE
    int*   bsum   = ssrc + EE;                     // 256
    int*   boff   = bsum + 256;                    // 256

    int* deg   = (int*)score;   // dead before k_score writes score
    int* spart = (int*)nmap;    // dead before nmap memset

    // output layout (all float32)
    float* out       = (float*)d_out;
    float* out_hp    = out;                                // 52480*128
    float* out_flat  = out_hp + (size_t)BBG * KKEEP * FF;  // 64*256
    float* out_edge  = out_flat + BBG * 256;               // 2*EE
    float* out_batch = out_edge + 2 * EE;                  // 52480

    hipMemsetAsync(deg, 0, (size_t)NN * sizeof(int), stream);
    hipMemsetAsync(stats, 0, 256 * sizeof(float), stream);

    k_deg<<<EE / 256, 256, 0, stream>>>(ei, deg);
    k_scan1<<<256, 256, 0, stream>>>(deg, spart, bsum);
    k_scan2<<<1, 256, 0, stream>>>(bsum, boff);
    k_scan3<<<256, 256, 0, stream>>>(deg, spart, boff, starts, cursor);
    k_scatter<<<EE / 256, 256, 0, stream>>>(ei, cursor, ssrc);

    hipMemsetAsync(nmap, 0xFF, (size_t)NN * sizeof(int), stream);  // spart dead now

    k_gemm3<<<NN / 128, 256, 0, stream>>>(x, Wl, Wr, bl, y, hz);
    k_hgather<<<NN / 32, 256, 0, stream>>>(y, ssrc, starts, hz, stats);
    k_score<<<NN / 8, 256, 0, stream>>>(hz, stats, gam, bet, attn, score);
    k_topk<<<BBG, 1024, 0, stream>>>(score, nmap, plist, out_batch);
    k_hp<<<(BBG * KKEEP) / 8, 256, 0, stream>>>(hz, score, plist, stats, gam, bet, out_hp);
    k_flat<<<BBG, 256, 0, stream>>>(out_hp, out_flat);
    k_edge<<<EE / 256, 256, 0, stream>>>(ei, nmap, out_edge);
}